// Round 6
// baseline (296.487 us; speedup 1.0000x reference)
//
#include <hip/hip_runtime.h>

// ---------------------------------------------------------------------------
// MultiQueryAttention: B=4 S=2048 E=1024 H=16 D=64 Q=4
// ref: q=x@Wq^T+bq (per qi), k=x@Wk^T+bk, v=x@Wv^T+bv
//      scores[qi,b,s,h,g] = dot_d(q[h],k[g])/8 ; softmax over g (16 heads!)
//      out[qi,b,s,h,d] = sum_g p*v[g,d]
//      t[b, 128h + s/16, 64(s%16)+d] = sum_qi out   (torch transpose+reshape)
//      final = t @ Wo^T + bo   (fp32 out)
// ---------------------------------------------------------------------------

typedef __bf16 bf16x8 __attribute__((ext_vector_type(8)));
typedef float f32x4 __attribute__((ext_vector_type(4)));
typedef float f32x16 __attribute__((ext_vector_type(16)));

__device__ __forceinline__ unsigned short f2b(float f) {
  unsigned u = __float_as_uint(f);
  return (unsigned short)((u + 0x7fffu + ((u >> 16) & 1u)) >> 16);  // RNE
}

__device__ __forceinline__ void async16(const void* g, void* l) {
  __builtin_amdgcn_global_load_lds(
      (const __attribute__((address_space(1))) void*)g,
      (__attribute__((address_space(3))) void*)l, 16, 0, 0);
}

// ------------------- fused fp32->bf16 convert + bias concat ------------------
__global__ __launch_bounds__(256) void cvt_all(
    const float* __restrict__ x, const float* __restrict__ Wq, const float* __restrict__ Wk,
    const float* __restrict__ Wv, const float* __restrict__ Wo, const float* __restrict__ bq,
    const float* __restrict__ bk, const float* __restrict__ bv,
    unsigned short* __restrict__ xb, unsigned short* __restrict__ wcat,
    unsigned short* __restrict__ wo_b, float* __restrict__ biascat) {
  if (blockIdx.x >= 15360) {
    int j = (blockIdx.x - 15360) * 256 + threadIdx.x;  // 0..6143
    if (j < 6144) {
      float v = (j < 4096) ? bq[j] : (j < 5120 ? bk[j - 4096] : bv[j - 5120]);
      biascat[j] = v;
    }
    return;
  }
  int i = blockIdx.x * 256 + threadIdx.x;
  const float* s;
  unsigned short* d;
  int off;
  if (i < 2097152)      { s = x;  d = xb;             off = i; }
  else if (i < 3145728) { s = Wq; d = wcat;           off = i - 2097152; }
  else if (i < 3407872) { s = Wk; d = wcat + 4194304; off = i - 3145728; }
  else if (i < 3670016) { s = Wv; d = wcat + 5242880; off = i - 3407872; }
  else                  { s = Wo; d = wo_b;           off = i - 3670016; }
  float4 v = ((const float4*)s)[off];
  uint2 o;
  o.x = (unsigned)f2b(v.x) | ((unsigned)f2b(v.y) << 16);
  o.y = (unsigned)f2b(v.z) | ((unsigned)f2b(v.w) << 16);
  ((uint2*)d)[off] = o;
}

// ------------------ 256x256 deep-pipelined GEMM (QKV) -----------------------
// C = A * Bt^T + bias, bf16 out. M%256==0, N%256==0, K%32==0, K>=64.
// 8 waves as 2(M)x4(N); per-wave C = 128x64 = 4x2 of 32x32 MFMA frags.
// LDS: 4-deep ring of BK=32 K-tiles (A:16KB + B:16KB each) = 128 KiB.
//
// PAIR-ROW SWIZZLE (R2, verified conflict-free: SQ_LDS_BANK_CONFLICT==0):
// granule g (16B) of row r lives at phys slot p = (2g+(r&1)) ^ ((r>>1)&7)
// within pair (r>>1). Store: linear LDS dest (global_load_lds), pre-swizzled
// GLOBAL source. Read: p = (4ks + 2*lhi + (l31&1)) ^ ((l31>>1)&7).
//
// R3 (verified best: 114.3us, MfmaUtil 39%): ONE barrier per K-tile, counted
// vmcnt(4), prefetch distance 1, staging mid-iteration. R4 (deeper prefetch)
// and R5 (setprio; only 1 block/CU resident -> nothing to arbitrate) both
// REGRESSED and are reverted.
// R6: CONSUMPTION-ORDER read/MFMA interleave. R3's source order (8 A-reads,
// then 4 B-reads, then 16 MFMA) makes the first MFMA depend on the wave's
// 9th read; under fair round-robin LDS arbitration of 96 reads/CU, every
// wave's MFMA stream therefore starts near the END of the ~1152cy read
// burst, serializing the ~1082cy/SIMD MFMA burst behind it (2850cy/iter
// measured = 1152+1082+overhead, MfmaUtil 39% = 1082/2850). Reordering so
// each MFMA's operands are read immediately before it gives dependency
// distance ~2 reads -> per-wave read/MFMA pipelining via the compiler's
// counted lgkmcnt cascade -> LDS and MFMA pipes overlap.
__global__ __launch_bounds__(512, 2) void gemm256(
    const unsigned short* __restrict__ A, const unsigned short* __restrict__ Bt,
    const float* __restrict__ bias, unsigned short* __restrict__ C,
    int M, int N, int K) {
  __shared__ __align__(16) unsigned short As[4][8192];
  __shared__ __align__(16) unsigned short Bs[4][8192];
  const int t = threadIdx.x;
  const int lane = t & 63, w = t >> 6;
  const int l31 = lane & 31, lhi = lane >> 5;
  const int wm = (w >> 2) * 128, wn = (w & 3) * 64;
  const int bm0 = blockIdx.y * 256, bn0 = blockIdx.x * 256;

  // ---- staging: thread t handles slot t (rows 0..127) and t+512 (rows
  // 128..255); source pre-swizzled, LDS dest linear.
  const int p0 = t & 7, pr0 = t >> 3;
  const int u0 = p0 ^ (pr0 & 7);
  const size_t aoff0 = (size_t)(2 * pr0 + (u0 & 1)) * K + (u0 >> 1) * 8;
  const unsigned short* aS0 = A + (size_t)bm0 * K + aoff0;
  const unsigned short* aS1 = aS0 + (size_t)128 * K;  // slot t+512: same u (64%8==0)
  const unsigned short* bS0 = Bt + (size_t)bn0 * K + aoff0;
  const unsigned short* bS1 = bS0 + (size_t)128 * K;
  const int d0 = t * 8, d1 = d0 + 4096;  // linear LDS dests (elements)

  // ---- read offsets
  const int plo = 2 * lhi + (l31 & 1);
  const int pswz = (l31 >> 1) & 7;
  const int pg0 = ((0 + plo) ^ pswz) * 8;  // ks=0
  const int pg1 = ((4 + plo) ^ pswz) * 8;  // ks=1
  int prA[4], prB[2];
#pragma unroll
  for (int mi = 0; mi < 4; ++mi) prA[mi] = ((wm + mi * 32 + l31) >> 1) * 64;
#pragma unroll
  for (int nj = 0; nj < 2; ++nj) prB[nj] = ((wn + nj * 32 + l31) >> 1) * 64;

  f32x16 acc[4][2];
#pragma unroll
  for (int mi = 0; mi < 4; ++mi)
#pragma unroll
    for (int nj = 0; nj < 2; ++nj)
#pragma unroll
      for (int e = 0; e < 16; ++e) acc[mi][nj][e] = 0.f;

#define STG_A(kt_) do { const int b_ = (kt_) & 3; const int ko_ = (kt_) * 32; \
    async16(aS0 + ko_, &As[b_][d0]); async16(aS1 + ko_, &As[b_][d1]); } while (0)
#define STG_B(kt_) do { const int b_ = (kt_) & 3; const int ko_ = (kt_) * 32; \
    async16(bS0 + ko_, &Bs[b_][d0]); async16(bS1 + ko_, &Bs[b_][d1]); } while (0)
#define MFMA(a_, b_, c_) c_ = __builtin_amdgcn_mfma_f32_32x32x16_bf16(a_, b_, c_, 0, 0, 0)

  const int NT = K >> 5;
  // prologue: tiles 0 and 1 in flight; retire tile 0 (tile 1's 4 stay out)
  STG_A(0); STG_B(0); STG_A(1); STG_B(1);
  asm volatile("s_waitcnt vmcnt(4)" ::: "memory");
  asm volatile("s_barrier" ::: "memory");

  for (int kt = 0; kt < NT; ++kt) {
    const int bi = kt & 3;
    const unsigned short* as_ = As[bi];
    const unsigned short* bs_ = Bs[bi];

    // ---- ks=0: consumption-ordered read/MFMA interleave ----
    bf16x8 b00 = *(const bf16x8*)(bs_ + prB[0] + pg0);
    bf16x8 a00 = *(const bf16x8*)(as_ + prA[0] + pg0);
    bf16x8 b10 = *(const bf16x8*)(bs_ + prB[1] + pg0);
    MFMA(a00, b00, acc[0][0]);
    bf16x8 a10 = *(const bf16x8*)(as_ + prA[1] + pg0);
    MFMA(a00, b10, acc[0][1]);
    bf16x8 a20 = *(const bf16x8*)(as_ + prA[2] + pg0);
    MFMA(a10, b00, acc[1][0]);
    MFMA(a10, b10, acc[1][1]);
    bf16x8 a30 = *(const bf16x8*)(as_ + prA[3] + pg0);
    MFMA(a20, b00, acc[2][0]);
    MFMA(a20, b10, acc[2][1]);

    // stage tile kt+2 mid-iteration (writes buffer kt-2: last read 2
    // barriers ago -> safe)
    if (kt + 2 < NT) { STG_A(kt + 2); STG_B(kt + 2); }

    MFMA(a30, b00, acc[3][0]);
    MFMA(a30, b10, acc[3][1]);

    // ---- ks=1 ----
    bf16x8 b01 = *(const bf16x8*)(bs_ + prB[0] + pg1);
    bf16x8 a01 = *(const bf16x8*)(as_ + prA[0] + pg1);
    bf16x8 b11 = *(const bf16x8*)(bs_ + prB[1] + pg1);
    MFMA(a01, b01, acc[0][0]);
    bf16x8 a11 = *(const bf16x8*)(as_ + prA[1] + pg1);
    MFMA(a01, b11, acc[0][1]);
    bf16x8 a21 = *(const bf16x8*)(as_ + prA[2] + pg1);
    MFMA(a11, b01, acc[1][0]);
    MFMA(a11, b11, acc[1][1]);
    bf16x8 a31 = *(const bf16x8*)(as_ + prA[3] + pg1);
    MFMA(a21, b01, acc[2][0]);
    MFMA(a21, b11, acc[2][1]);
    MFMA(a31, b01, acc[3][0]);
    MFMA(a31, b11, acc[3][1]);

    // counted wait: retire tile kt+1's 4 loads (oldest); keep tile kt+2's 4
    // in flight. Tail: drain only when nothing newer was issued.
    if (kt + 2 < NT) {
      asm volatile("s_waitcnt vmcnt(4)" ::: "memory");
    } else if (kt + 1 < NT) {
      asm volatile("s_waitcnt vmcnt(0)" ::: "memory");
    }
    asm volatile("s_barrier" ::: "memory");
  }
#undef STG_A
#undef STG_B
#undef MFMA

  // epilogue: col = l31, row = (reg&3) + 8*(reg>>2) + 4*lhi
#pragma unroll
  for (int mi = 0; mi < 4; ++mi) {
#pragma unroll
    for (int nj = 0; nj < 2; ++nj) {
      int gc = bn0 + wn + nj * 32 + l31;
      float bsv = bias[gc];
#pragma unroll
      for (int reg = 0; reg < 16; ++reg) {
        int gr = bm0 + wm + mi * 32 + (reg & 3) + 8 * (reg >> 2) + 4 * lhi;
        C[(size_t)gr * N + gc] = f2b(acc[mi][nj][reg] + bsv);
      }
    }
  }
}

// --------------------------- C = A * Bt^T + bias ----------------------------
// (128x128 tile, kept for the final projection where N=1024 would underfill
// the grid at 256^2.)
template <typename OutT>
__global__ __launch_bounds__(256) void gemm_bt(const unsigned short* __restrict__ A,
                                               const unsigned short* __restrict__ Bt,
                                               const float* __restrict__ bias,
                                               OutT* __restrict__ C, int M, int N, int K) {
  __shared__ __align__(16) unsigned short As[128 * 64];
  __shared__ __align__(16) unsigned short Bs[128 * 64];
  const int t = threadIdx.x;
  const int lane = t & 63, w = t >> 6;
  const int wm = (w >> 1) * 64, wn = (w & 1) * 64;
  const int l31 = lane & 31, lhi = lane >> 5;
  const int bm0 = blockIdx.y * 128, bn0 = blockIdx.x * 128;

  f32x16 acc[2][2];
#pragma unroll
  for (int i = 0; i < 2; ++i)
#pragma unroll
    for (int j = 0; j < 2; ++j)
#pragma unroll
      for (int e = 0; e < 16; ++e) acc[i][j][e] = 0.f;

  const int swz = l31 & 7;
  const int qoff = 2 * ((l31 >> 4) & 1);

  for (int k0 = 0; k0 < K; k0 += 64) {
    __syncthreads();
#pragma unroll
    for (int j = 0; j < 4; ++j) {
      int slot = j * 256 + t;
      int r = slot >> 3;
      int p = slot & 7;
      int c = (((p ^ (r & 7)) - 2 * ((r >> 4) & 1)) & 7) * 8;
      async16(A + (size_t)(bm0 + r) * K + k0 + c, As + slot * 8);
      async16(Bt + (size_t)(bn0 + r) * K + k0 + c, Bs + slot * 8);
    }
    __syncthreads();
#pragma unroll
    for (int kk = 0; kk < 64; kk += 16) {
      const int kg = kk >> 3;
      const int pg = ((((kg + lhi + qoff) & 7) ^ swz) << 3);
      bf16x8 af[2], bfr[2];
#pragma unroll
      for (int i = 0; i < 2; ++i)
        af[i] = *(const bf16x8*)(As + (wm + i * 32 + l31) * 64 + pg);
#pragma unroll
      for (int j = 0; j < 2; ++j)
        bfr[j] = *(const bf16x8*)(Bs + (wn + j * 32 + l31) * 64 + pg);
#pragma unroll
      for (int i = 0; i < 2; ++i)
#pragma unroll
        for (int j = 0; j < 2; ++j)
          acc[i][j] = __builtin_amdgcn_mfma_f32_32x32x16_bf16(af[i], bfr[j], acc[i][j], 0, 0, 0);
    }
  }

#pragma unroll
  for (int i = 0; i < 2; ++i) {
#pragma unroll
    for (int j = 0; j < 2; ++j) {
      int gc = bn0 + wn + j * 32 + l31;
      float bsv = bias[gc];
#pragma unroll
      for (int reg = 0; reg < 16; ++reg) {
        int gr = bm0 + wm + i * 32 + (reg & 3) + 8 * (reg >> 2) + 4 * lhi;
        float vv = acc[i][j][reg] + bsv;
        if constexpr (sizeof(OutT) == 2)
          C[(size_t)gr * N + gc] = (OutT)f2b(vv);
        else
          C[(size_t)gr * N + gc] = vv;
      }
    }
  }
}

// ------------------- per-position head-softmax attention --------------------
__global__ __launch_bounds__(256) void attn_scatter(const unsigned short* __restrict__ qkv,
                                                    unsigned short* __restrict__ t) {
  __shared__ __align__(16) unsigned short vs[4][1024];
  __shared__ float ps[4][16 * 17];
  const int w = threadIdx.x >> 6, lane = threadIdx.x & 63;
  const int pos = blockIdx.x * 4 + w;  // 0..8191
  const int b = pos >> 11, s = pos & 2047;
  const unsigned short* row = qkv + (size_t)pos * 6144;
  unsigned short* vw = vs[w];
  float* pw = ps[w];
  const int lr = lane & 15, lq = lane >> 4;

  {
    const uint4* sv = (const uint4*)(row + 5120);
    uint4* dv = (uint4*)vw;
    dv[lane * 2] = sv[lane * 2];
    dv[lane * 2 + 1] = sv[lane * 2 + 1];
  }
  bf16x8 kf0 = *(const bf16x8*)(row + 4096 + lr * 64 + lq * 8);
  bf16x8 kf1 = *(const bf16x8*)(row + 4096 + lr * 64 + 32 + lq * 8);

  bf16x8 vf[4];
#pragma unroll
  for (int dc = 0; dc < 4; ++dc) {
#pragma unroll
    for (int j = 0; j < 8; ++j) vf[dc][j] = (__bf16)0.0f;
    if (lq < 2) {
      const __bf16* vb = (const __bf16*)vw;
#pragma unroll
      for (int j = 0; j < 8; ++j)
        vf[dc][j] = vb[(lq * 8 + j) * 64 + dc * 16 + lr];
    }
  }

  f32x4 acc[4];
#pragma unroll
  for (int dc = 0; dc < 4; ++dc) acc[dc] = (f32x4){0.f, 0.f, 0.f, 0.f};

#pragma unroll
  for (int qi = 0; qi < 4; ++qi) {
    bf16x8 qf0 = *(const bf16x8*)(row + qi * 1024 + lr * 64 + lq * 8);
    bf16x8 qf1 = *(const bf16x8*)(row + qi * 1024 + lr * 64 + 32 + lq * 8);
    f32x4 sc = {0.f, 0.f, 0.f, 0.f};
    sc = __builtin_amdgcn_mfma_f32_16x16x32_bf16(qf0, kf0, sc, 0, 0, 0);
    sc = __builtin_amdgcn_mfma_f32_16x16x32_bf16(qf1, kf1, sc, 0, 0, 0);
#pragma unroll
    for (int r = 0; r < 4; ++r) {
      float e = __expf(sc[r] * 0.125f);
      float sum = e;
#pragma unroll
      for (int d = 1; d < 16; d <<= 1) sum += __shfl_xor(sum, d);
      pw[(lq * 4 + r) * 17 + lr] = e / sum;
    }
    bf16x8 pf;
#pragma unroll
    for (int j = 0; j < 8; ++j) pf[j] = (__bf16)0.0f;
    if (lq < 2) {
#pragma unroll
      for (int j = 0; j < 8; ++j) pf[j] = (__bf16)pw[lr * 17 + lq * 8 + j];
    }
#pragma unroll
    for (int dc = 0; dc < 4; ++dc)
      acc[dc] = __builtin_amdgcn_mfma_f32_16x16x32_bf16(vf[dc], pf, acc[dc], 0, 0, 0);
  }

  size_t base = ((size_t)(b * 2048 + 128 * lr + (s >> 4))) * 1024 + 64 * (s & 15) + lq * 4;
#pragma unroll
  for (int dc = 0; dc < 4; ++dc) {
    uint2 u;
    u.x = (unsigned)f2b(acc[dc][0]) | ((unsigned)f2b(acc[dc][1]) << 16);
    u.y = (unsigned)f2b(acc[dc][2]) | ((unsigned)f2b(acc[dc][3]) << 16);
    *(uint2*)(t + base + dc * 16) = u;
  }
}

// ---------------------------------------------------------------------------
extern "C" void kernel_launch(void* const* d_in, const int* in_sizes, int n_in,
                              void* d_out, int out_size, void* d_ws, size_t ws_size,
                              hipStream_t stream) {
  const float* x  = (const float*)d_in[0];
  const float* Wq = (const float*)d_in[1];
  const float* bq = (const float*)d_in[2];
  const float* Wk = (const float*)d_in[3];
  const float* bk = (const float*)d_in[4];
  const float* Wv = (const float*)d_in[5];
  const float* bv = (const float*)d_in[6];
  const float* Wo = (const float*)d_in[7];
  const float* bo = (const float*)d_in[8];
  float* out = (float*)d_out;

  char* ws = (char*)d_ws;
  unsigned short* xb      = (unsigned short*)(ws + 0);         // 8192x1024 bf16 (16MB); aliased as t later
  unsigned short* wcat    = (unsigned short*)(ws + 16777216);  // 6144x1024 bf16 (12MB): Wq|Wk|Wv
  unsigned short* wo_b    = (unsigned short*)(ws + 29360128);  // 1024x1024 bf16 (2MB)
  float*          biascat = (float*)(ws + 31457280);           // 6144 fp32
  unsigned short* qkv     = (unsigned short*)(ws + 31481856);  // 8192x6144 bf16 (96MB)
  unsigned short* t       = xb;  // safe alias: xb dead after QKV GEMM

  cvt_all<<<15384, 256, 0, stream>>>(x, Wq, Wk, Wv, Wo, bq, bk, bv, xb, wcat, wo_b, biascat);

  // QKV: (8192x1024) x (6144x1024)^T -> 8192x6144 bf16  (256^2 deep pipeline)
  gemm256<<<dim3(24, 32), 512, 0, stream>>>(xb, wcat, biascat, qkv, 8192, 6144, 1024);
  // attention + permute/sum scatter -> t (8192x1024 bf16)
  attn_scatter<<<2048, 256, 0, stream>>>(qkv, t);
  // final: t x Wo^T + bo -> fp32 out
  gemm_bt<float><<<dim3(8, 64), 256, 0, stream>>>(t, wo_b, bo, out, 8192, 1024, 1024);
}

// Round 8
// 290.529 us; speedup vs baseline: 1.0205x; 1.0205x over previous
//
#include <hip/hip_runtime.h>

// ---------------------------------------------------------------------------
// MultiQueryAttention: B=4 S=2048 E=1024 H=16 D=64 Q=4
// ref: q=x@Wq^T+bq (per qi), k=x@Wk^T+bk, v=x@Wv^T+bv
//      scores[qi,b,s,h,g] = dot_d(q[h],k[g])/8 ; softmax over g (16 heads!)
//      out[qi,b,s,h,d] = sum_g p*v[g,d]
//      t[b, 128h + s/16, 64(s%16)+d] = sum_qi out   (torch transpose+reshape)
//      final = t @ Wo^T + bo   (fp32 out)
// ---------------------------------------------------------------------------

typedef __bf16 bf16x8 __attribute__((ext_vector_type(8)));
typedef float f32x4 __attribute__((ext_vector_type(4)));
typedef float f32x16 __attribute__((ext_vector_type(16)));

__device__ __forceinline__ unsigned short f2b(float f) {
  unsigned u = __float_as_uint(f);
  return (unsigned short)((u + 0x7fffu + ((u >> 16) & 1u)) >> 16);  // RNE
}

__device__ __forceinline__ void async16(const void* g, void* l) {
  __builtin_amdgcn_global_load_lds(
      (const __attribute__((address_space(1))) void*)g,
      (__attribute__((address_space(3))) void*)l, 16, 0, 0);
}

// ------------------- fused fp32->bf16 convert + bias concat ------------------
__global__ __launch_bounds__(256) void cvt_all(
    const float* __restrict__ x, const float* __restrict__ Wq, const float* __restrict__ Wk,
    const float* __restrict__ Wv, const float* __restrict__ Wo, const float* __restrict__ bq,
    const float* __restrict__ bk, const float* __restrict__ bv,
    unsigned short* __restrict__ xb, unsigned short* __restrict__ wcat,
    unsigned short* __restrict__ wo_b, float* __restrict__ biascat) {
  if (blockIdx.x >= 15360) {
    int j = (blockIdx.x - 15360) * 256 + threadIdx.x;  // 0..6143
    if (j < 6144) {
      float v = (j < 4096) ? bq[j] : (j < 5120 ? bk[j - 4096] : bv[j - 5120]);
      biascat[j] = v;
    }
    return;
  }
  int i = blockIdx.x * 256 + threadIdx.x;
  const float* s;
  unsigned short* d;
  int off;
  if (i < 2097152)      { s = x;  d = xb;             off = i; }
  else if (i < 3145728) { s = Wq; d = wcat;           off = i - 2097152; }
  else if (i < 3407872) { s = Wk; d = wcat + 4194304; off = i - 3145728; }
  else if (i < 3670016) { s = Wv; d = wcat + 5242880; off = i - 3407872; }
  else                  { s = Wo; d = wo_b;           off = i - 3670016; }
  float4 v = ((const float4*)s)[off];
  uint2 o;
  o.x = (unsigned)f2b(v.x) | ((unsigned)f2b(v.y) << 16);
  o.y = (unsigned)f2b(v.z) | ((unsigned)f2b(v.w) << 16);
  ((uint2*)d)[off] = o;
}

// ------------- 256x256 8-phase deep-pipelined GEMM (QKV, R7) ----------------
// C = A * Bt^T + bias, bf16 out. Faithful port of the verified m201 8-phase
// template (T2+T3+T4+T5) to 32x32x16 MFMA. Requires M%256==0, N%256==0,
// K%128==0, K>=256.
//
// Geometry: 8 waves 2(M)x4(N); per-wave C = 128x64 = 4(mi)x2(nj) frags of
// 32x32. BK=64; LDS = 2 buffers x (A 32KB + B 32KB) = 128 KiB; buf0 holds
// even K-tiles, buf1 odd.
//
// Swizzle (BK=64 row = 128B = all 32 banks): granule g (16B) of row r at
// phys p = g ^ (r&7). Store side: linear LDS dest (global_load_lds), the
// global SOURCE is pre-swizzled; read side applies the same XOR (rule #21).
// Enumeration: per frag-read, 8 lanes per granule-group, uniform -> 0-conflict.
//
// Iteration i = K-tiles (2i, 2i+1) = 8 phases. Phase = one C-quadrant
// (mh,nh) x K=64 = 8 MFMA; order (0,0)->(0,1)->(1,1)->(1,0) reuses B-frags in
// registers (reads/phase: 12/4/8/0). Phase shape (m201): {stage 1 unit;
// ds_reads; s_barrier; lgkmcnt(0); sched_barrier(0); setprio(1); 8 MFMA;
// setprio(0); s_barrier}. Overlap mechanism: waves cross the post-MFMA
// barrier at ISSUE time, so the matrix-pipe drain of phase p overlaps the
// LDS read burst of phase p+1 (R3's single-region structure serialized
// these: 39% MfmaUtil; R4/R5/R6 hand-scheduling variants all regressed).
//
// Staging: 16KB units, 2 global_load_lds per phase. Unit free-map (last
// reader >= 1 barrier before the stage):
//   ph1: U_A2' buf1 kt=2i+1 (read prev ph7)   ph5: U_A2 buf0 kt=2i+2 (ph3)
//   ph2: U_A1  buf0 kt=2i+2 (read ph1)        ph6: U_A1' buf1 kt=2i+3 (ph5)
//   ph3: U_B1  buf0 kt=2i+2 (read ph1)        ph7: U_B1' buf1 kt=2i+3 (ph5)
//   ph4: U_B2  buf0 kt=2i+2 (read ph2)        ph8: U_B2' buf1 kt=2i+3 (ph6)
// vmcnt(6) at phases 4 and 8 only (retires everything older than the 3
// newest units; all data consumed next is then landed — checked per-unit).
// Tail (last iter): stages stop, vmcnt(0) once.
__global__ __launch_bounds__(512, 2) void gemm256(
    const unsigned short* __restrict__ A, const unsigned short* __restrict__ Bt,
    const float* __restrict__ bias, unsigned short* __restrict__ C,
    int M, int N, int K) {
  __shared__ __align__(16) unsigned short As[2][16384];
  __shared__ __align__(16) unsigned short Bs[2][16384];
  const int t = threadIdx.x;
  const int lane = t & 63, w = t >> 6;
  const int l31 = lane & 31, lhi = lane >> 5;
  const int wm = (w >> 2) * 128, wn = (w & 3) * 64;
  const int bm0 = blockIdx.y * 256, bn0 = blockIdx.x * 256;
  unsigned short* As0 = &As[0][0];
  unsigned short* As1 = &As[1][0];
  unsigned short* Bs0 = &Bs[0][0];
  unsigned short* Bs1 = &Bs[1][0];

  // ---- staging constants: thread t handles 2 rows per unit, phys granule
  // t&7; pre-swizzled global source: logical granule = (t&7) ^ (row&7).
  // All units use rows r = base + {0,32,64,...} (multiples of 8) from
  // r0/rb, so row&7 == r0&7 for every load. LDS dest offset = 8t elems =
  // wave-uniform base + 16B*lane (rule #21 linearity requirement).
  const int r0 = t >> 3;                       // 0..63
  const int p8 = (t & 7) * 8;                  // phys granule elem offset
  const int gsw = ((t & 7) ^ (r0 & 7)) * 8;    // pre-swizzled logical offset
  const int rb = ((r0 >> 5) << 6) + (r0 & 31); // B-unit row base (0-31,64-95)
  const unsigned short* aG = A + (size_t)bm0 * K;
  const unsigned short* bG = Bt + (size_t)bn0 * K;

#define STG2(G_, L_, ra_, rb_, kt_) do {                                  \
    const size_t ko_ = (size_t)(kt_) * 64 + gsw;                          \
    async16(G_ + (size_t)(ra_) * K + ko_, L_ + (ra_) * 64 + p8);          \
    async16(G_ + (size_t)(rb_) * K + ko_, L_ + (rb_) * 64 + p8);          \
  } while (0)
#define MFMA(a_, b_, c_) c_ = __builtin_amdgcn_mfma_f32_32x32x16_bf16(a_, b_, c_, 0, 0, 0)
#define BAR() asm volatile("s_barrier" ::: "memory")
#define WAIT_LDS() do { asm volatile("s_waitcnt lgkmcnt(0)" ::: "memory"); \
    __builtin_amdgcn_sched_barrier(0); } while (0)

  // ---- read offsets (buffer-relative, row stride 64 elems)
  int prA[4], prB[2], pg[4];
#pragma unroll
  for (int mi = 0; mi < 4; ++mi) prA[mi] = (wm + mi * 32 + l31) * 64;
#pragma unroll
  for (int nj = 0; nj < 2; ++nj) prB[nj] = (wn + nj * 32 + l31) * 64;
#pragma unroll
  for (int ks = 0; ks < 4; ++ks) pg[ks] = ((2 * ks + lhi) ^ (l31 & 7)) * 8;

  f32x16 acc[4][2];
#pragma unroll
  for (int mi = 0; mi < 4; ++mi)
#pragma unroll
    for (int nj = 0; nj < 2; ++nj)
#pragma unroll
      for (int e = 0; e < 16; ++e) acc[mi][nj][e] = 0.f;

  const int NI = K >> 7;  // iterations of 2 K-tiles; NI>=2 required
  // prologue: K-tile 0 all 4 units -> buf0; K-tile 1 units A1',B1',B2' -> buf1
  STG2(aG, As0, r0, r0 + 128, 0);          // U_A1
  STG2(aG, As0, r0 + 64, r0 + 192, 0);     // U_A2
  STG2(bG, Bs0, rb, rb + 128, 0);          // U_B1
  STG2(bG, Bs0, rb + 32, rb + 160, 0);     // U_B2
  STG2(aG, As1, r0, r0 + 128, 1);          // U_A1'
  STG2(bG, Bs1, rb, rb + 128, 1);          // U_B1'
  STG2(bG, Bs1, rb + 32, rb + 160, 1);     // U_B2'
  asm volatile("s_waitcnt vmcnt(6)" ::: "memory");
  BAR();

  for (int i = 0; i < NI; ++i) {
    const bool pf = (i + 1 < NI);
    {  // ================== K-tile 2i (buf0), phases 1-4 ==================
      // ---- phase 1: quadrant (0,0) ----
      STG2(aG, As1, r0 + 64, r0 + 192, 2 * i + 1);  // U_A2' (always valid)
      bf16x8 a01[2][4], b0[4];
#pragma unroll
      for (int ks = 0; ks < 4; ++ks) {
        a01[0][ks] = *(const bf16x8*)(As0 + prA[0] + pg[ks]);
        a01[1][ks] = *(const bf16x8*)(As0 + prA[1] + pg[ks]);
        b0[ks]     = *(const bf16x8*)(Bs0 + prB[0] + pg[ks]);
      }
      BAR(); WAIT_LDS();
      __builtin_amdgcn_s_setprio(1);
#pragma unroll
      for (int ks = 0; ks < 4; ++ks) {
        MFMA(a01[0][ks], b0[ks], acc[0][0]);
        MFMA(a01[1][ks], b0[ks], acc[1][0]);
      }
      __builtin_amdgcn_s_setprio(0);
      BAR();

      // ---- phase 2: quadrant (0,1) ----
      if (pf) STG2(aG, As0, r0, r0 + 128, 2 * i + 2);  // U_A1
      bf16x8 b1[4];
#pragma unroll
      for (int ks = 0; ks < 4; ++ks) b1[ks] = *(const bf16x8*)(Bs0 + prB[1] + pg[ks]);
      BAR(); WAIT_LDS();
      __builtin_amdgcn_s_setprio(1);
#pragma unroll
      for (int ks = 0; ks < 4; ++ks) {
        MFMA(a01[0][ks], b1[ks], acc[0][1]);
        MFMA(a01[1][ks], b1[ks], acc[1][1]);
      }
      __builtin_amdgcn_s_setprio(0);
      BAR();

      // ---- phase 3: quadrant (1,1) ----
      if (pf) STG2(bG, Bs0, rb, rb + 128, 2 * i + 2);  // U_B1
      bf16x8 a23[2][4];
#pragma unroll
      for (int ks = 0; ks < 4; ++ks) {
        a23[0][ks] = *(const bf16x8*)(As0 + prA[2] + pg[ks]);
        a23[1][ks] = *(const bf16x8*)(As0 + prA[3] + pg[ks]);
      }
      BAR(); WAIT_LDS();
      __builtin_amdgcn_s_setprio(1);
#pragma unroll
      for (int ks = 0; ks < 4; ++ks) {
        MFMA(a23[0][ks], b1[ks], acc[2][1]);
        MFMA(a23[1][ks], b1[ks], acc[3][1]);
      }
      __builtin_amdgcn_s_setprio(0);
      BAR();

      // ---- phase 4: quadrant (1,0) — no reads ----
      if (pf) STG2(bG, Bs0, rb + 32, rb + 160, 2 * i + 2);  // U_B2
      __builtin_amdgcn_s_setprio(1);
#pragma unroll
      for (int ks = 0; ks < 4; ++ks) {
        MFMA(a23[0][ks], b0[ks], acc[2][0]);
        MFMA(a23[1][ks], b0[ks], acc[3][0]);
      }
      __builtin_amdgcn_s_setprio(0);
      if (pf) asm volatile("s_waitcnt vmcnt(6)" ::: "memory");
      else    asm volatile("s_waitcnt vmcnt(0)" ::: "memory");
      BAR();
    }
    {  // ================= K-tile 2i+1 (buf1), phases 5-8 =================
      // ---- phase 5: quadrant (0,0) ----
      if (pf) STG2(aG, As0, r0 + 64, r0 + 192, 2 * i + 2);  // U_A2
      bf16x8 a01[2][4], b0[4];
#pragma unroll
      for (int ks = 0; ks < 4; ++ks) {
        a01[0][ks] = *(const bf16x8*)(As1 + prA[0] + pg[ks]);
        a01[1][ks] = *(const bf16x8*)(As1 + prA[1] + pg[ks]);
        b0[ks]     = *(const bf16x8*)(Bs1 + prB[0] + pg[ks]);
      }
      BAR(); WAIT_LDS();
      __builtin_amdgcn_s_setprio(1);
#pragma unroll
      for (int ks = 0; ks < 4; ++ks) {
        MFMA(a01[0][ks], b0[ks], acc[0][0]);
        MFMA(a01[1][ks], b0[ks], acc[1][0]);
      }
      __builtin_amdgcn_s_setprio(0);
      BAR();

      // ---- phase 6: quadrant (0,1) ----
      if (pf) STG2(aG, As1, r0, r0 + 128, 2 * i + 3);  // U_A1'
      bf16x8 b1[4];
#pragma unroll
      for (int ks = 0; ks < 4; ++ks) b1[ks] = *(const bf16x8*)(Bs1 + prB[1] + pg[ks]);
      BAR(); WAIT_LDS();
      __builtin_amdgcn_s_setprio(1);
#pragma unroll
      for (int ks = 0; ks < 4; ++ks) {
        MFMA(a01[0][ks], b1[ks], acc[0][1]);
        MFMA(a01[1][ks], b1[ks], acc[1][1]);
      }
      __builtin_amdgcn_s_setprio(0);
      BAR();

      // ---- phase 7: quadrant (1,1) ----
      if (pf) STG2(bG, Bs1, rb, rb + 128, 2 * i + 3);  // U_B1'
      bf16x8 a23[2][4];
#pragma unroll
      for (int ks = 0; ks < 4; ++ks) {
        a23[0][ks] = *(const bf16x8*)(As1 + prA[2] + pg[ks]);
        a23[1][ks] = *(const bf16x8*)(As1 + prA[3] + pg[ks]);
      }
      BAR(); WAIT_LDS();
      __builtin_amdgcn_s_setprio(1);
#pragma unroll
      for (int ks = 0; ks < 4; ++ks) {
        MFMA(a23[0][ks], b1[ks], acc[2][1]);
        MFMA(a23[1][ks], b1[ks], acc[3][1]);
      }
      __builtin_amdgcn_s_setprio(0);
      BAR();

      // ---- phase 8: quadrant (1,0) — no reads ----
      if (pf) STG2(bG, Bs1, rb + 32, rb + 160, 2 * i + 3);  // U_B2'
      __builtin_amdgcn_s_setprio(1);
#pragma unroll
      for (int ks = 0; ks < 4; ++ks) {
        MFMA(a23[0][ks], b0[ks], acc[2][0]);
        MFMA(a23[1][ks], b0[ks], acc[3][0]);
      }
      __builtin_amdgcn_s_setprio(0);
      if (pf) asm volatile("s_waitcnt vmcnt(6)" ::: "memory");
      else    asm volatile("s_waitcnt vmcnt(0)" ::: "memory");
      BAR();
    }
  }
#undef STG2
#undef MFMA
#undef BAR
#undef WAIT_LDS

  // epilogue: col = l31, row = (reg&3) + 8*(reg>>2) + 4*lhi
#pragma unroll
  for (int mi = 0; mi < 4; ++mi) {
#pragma unroll
    for (int nj = 0; nj < 2; ++nj) {
      int gc = bn0 + wn + nj * 32 + l31;
      float bsv = bias[gc];
#pragma unroll
      for (int reg = 0; reg < 16; ++reg) {
        int gr = bm0 + wm + mi * 32 + (reg & 3) + 8 * (reg >> 2) + 4 * lhi;
        C[(size_t)gr * N + gc] = f2b(acc[mi][nj][reg] + bsv);
      }
    }
  }
}

// --------------------------- C = A * Bt^T + bias ----------------------------
// (128x128 tile, kept for the final projection where N=1024 would underfill
// the grid at 256^2.)
template <typename OutT>
__global__ __launch_bounds__(256) void gemm_bt(const unsigned short* __restrict__ A,
                                               const unsigned short* __restrict__ Bt,
                                               const float* __restrict__ bias,
                                               OutT* __restrict__ C, int M, int N, int K) {
  __shared__ __align__(16) unsigned short As[128 * 64];
  __shared__ __align__(16) unsigned short Bs[128 * 64];
  const int t = threadIdx.x;
  const int lane = t & 63, w = t >> 6;
  const int wm = (w >> 1) * 64, wn = (w & 1) * 64;
  const int l31 = lane & 31, lhi = lane >> 5;
  const int bm0 = blockIdx.y * 128, bn0 = blockIdx.x * 128;

  f32x16 acc[2][2];
#pragma unroll
  for (int i = 0; i < 2; ++i)
#pragma unroll
    for (int j = 0; j < 2; ++j)
#pragma unroll
      for (int e = 0; e < 16; ++e) acc[i][j][e] = 0.f;

  const int swz = l31 & 7;
  const int qoff = 2 * ((l31 >> 4) & 1);

  for (int k0 = 0; k0 < K; k0 += 64) {
    __syncthreads();
#pragma unroll
    for (int j = 0; j < 4; ++j) {
      int slot = j * 256 + t;
      int r = slot >> 3;
      int p = slot & 7;
      int c = (((p ^ (r & 7)) - 2 * ((r >> 4) & 1)) & 7) * 8;
      async16(A + (size_t)(bm0 + r) * K + k0 + c, As + slot * 8);
      async16(Bt + (size_t)(bn0 + r) * K + k0 + c, Bs + slot * 8);
    }
    __syncthreads();
#pragma unroll
    for (int kk = 0; kk < 64; kk += 16) {
      const int kg = kk >> 3;
      const int pg = ((((kg + lhi + qoff) & 7) ^ swz) << 3);
      bf16x8 af[2], bfr[2];
#pragma unroll
      for (int i = 0; i < 2; ++i)
        af[i] = *(const bf16x8*)(As + (wm + i * 32 + l31) * 64 + pg);
#pragma unroll
      for (int j = 0; j < 2; ++j)
        bfr[j] = *(const bf16x8*)(Bs + (wn + j * 32 + l31) * 64 + pg);
#pragma unroll
      for (int i = 0; i < 2; ++i)
#pragma unroll
        for (int j = 0; j < 2; ++j)
          acc[i][j] = __builtin_amdgcn_mfma_f32_32x32x16_bf16(af[i], bfr[j], acc[i][j], 0, 0, 0);
    }
  }

#pragma unroll
  for (int i = 0; i < 2; ++i) {
#pragma unroll
    for (int j = 0; j < 2; ++j) {
      int gc = bn0 + wn + j * 32 + l31;
      float bsv = bias[gc];
#pragma unroll
      for (int reg = 0; reg < 16; ++reg) {
        int gr = bm0 + wm + i * 32 + (reg & 3) + 8 * (reg >> 2) + 4 * lhi;
        float vv = acc[i][j][reg] + bsv;
        if constexpr (sizeof(OutT) == 2)
          C[(size_t)gr * N + gc] = (OutT)f2b(vv);
        else
          C[(size_t)gr * N + gc] = vv;
      }
    }
  }
}

// ------------------- per-position head-softmax attention --------------------
__global__ __launch_bounds__(256) void attn_scatter(const unsigned short* __restrict__ qkv,
                                                    unsigned short* __restrict__ t) {
  __shared__ __align__(16) unsigned short vs[4][1024];
  __shared__ float ps[4][16 * 17];
  const int w = threadIdx.x >> 6, lane = threadIdx.x & 63;
  const int pos = blockIdx.x * 4 + w;  // 0..8191
  const int b = pos >> 11, s = pos & 2047;
  const unsigned short* row = qkv + (size_t)pos * 6144;
  unsigned short* vw = vs[w];
  float* pw = ps[w];
  const int lr = lane & 15, lq = lane >> 4;

  {
    const uint4* sv = (const uint4*)(row + 5120);
    uint4* dv = (uint4*)vw;
    dv[lane * 2] = sv[lane * 2];
    dv[lane * 2 + 1] = sv[lane * 2 + 1];
  }
  bf16x8 kf0 = *(const bf16x8*)(row + 4096 + lr * 64 + lq * 8);
  bf16x8 kf1 = *(const bf16x8*)(row + 4096 + lr * 64 + 32 + lq * 8);

  bf16x8 vf[4];
#pragma unroll
  for (int dc = 0; dc < 4; ++dc) {
#pragma unroll
    for (int j = 0; j < 8; ++j) vf[dc][j] = (__bf16)0.0f;
    if (lq < 2) {
      const __bf16* vb = (const __bf16*)vw;
#pragma unroll
      for (int j = 0; j < 8; ++j)
        vf[dc][j] = vb[(lq * 8 + j) * 64 + dc * 16 + lr];
    }
  }

  f32x4 acc[4];
#pragma unroll
  for (int dc = 0; dc < 4; ++dc) acc[dc] = (f32x4){0.f, 0.f, 0.f, 0.f};

#pragma unroll
  for (int qi = 0; qi < 4; ++qi) {
    bf16x8 qf0 = *(const bf16x8*)(row + qi * 1024 + lr * 64 + lq * 8);
    bf16x8 qf1 = *(const bf16x8*)(row + qi * 1024 + lr * 64 + 32 + lq * 8);
    f32x4 sc = {0.f, 0.f, 0.f, 0.f};
    sc = __builtin_amdgcn_mfma_f32_16x16x32_bf16(qf0, kf0, sc, 0, 0, 0);
    sc = __builtin_amdgcn_mfma_f32_16x16x32_bf16(qf1, kf1, sc, 0, 0, 0);
#pragma unroll
    for (int r = 0; r < 4; ++r) {
      float e = __expf(sc[r] * 0.125f);
      float sum = e;
#pragma unroll
      for (int d = 1; d < 16; d <<= 1) sum += __shfl_xor(sum, d);
      pw[(lq * 4 + r) * 17 + lr] = e / sum;
    }
    bf16x8 pf;
#pragma unroll
    for (int j = 0; j < 8; ++j) pf[j] = (__bf16)0.0f;
    if (lq < 2) {
#pragma unroll
      for (int j = 0; j < 8; ++j) pf[j] = (__bf16)pw[lr * 17 + lq * 8 + j];
    }
#pragma unroll
    for (int dc = 0; dc < 4; ++dc)
      acc[dc] = __builtin_amdgcn_mfma_f32_16x16x32_bf16(vf[dc], pf, acc[dc], 0, 0, 0);
  }

  size_t base = ((size_t)(b * 2048 + 128 * lr + (s >> 4))) * 1024 + 64 * (s & 15) + lq * 4;
#pragma unroll
  for (int dc = 0; dc < 4; ++dc) {
    uint2 u;
    u.x = (unsigned)f2b(acc[dc][0]) | ((unsigned)f2b(acc[dc][1]) << 16);
    u.y = (unsigned)f2b(acc[dc][2]) | ((unsigned)f2b(acc[dc][3]) << 16);
    *(uint2*)(t + base + dc * 16) = u;
  }
}

// ---------------------------------------------------------------------------
extern "C" void kernel_launch(void* const* d_in, const int* in_sizes, int n_in,
                              void* d_out, int out_size, void* d_ws, size_t ws_size,
                              hipStream_t stream) {
  const float* x  = (const float*)d_in[0];
  const float* Wq = (const float*)d_in[1];
  const float* bq = (const float*)d_in[2];
  const float* Wk = (const float*)d_in[3];
  const float* bk = (const float*)d_in[4];
  const float* Wv = (const float*)d_in[5];
  const float* bv = (const float*)d_in[6];
  const float* Wo = (const float*)d_in[7];
  const float* bo = (const float*)d_in[8];
  float* out = (float*)d_out;

  char* ws = (char*)d_ws;
  unsigned short* xb      = (unsigned short*)(ws + 0);         // 8192x1024 bf16 (16MB); aliased as t later
  unsigned short* wcat    = (unsigned short*)(ws + 16777216);  // 6144x1024 bf16 (12MB): Wq|Wk|Wv
  unsigned short* wo_b    = (unsigned short*)(ws + 29360128);  // 1024x1024 bf16 (2MB)
  float*          biascat = (float*)(ws + 31457280);           // 6144 fp32
  unsigned short* qkv     = (unsigned short*)(ws + 31481856);  // 8192x6144 bf16 (96MB)
  unsigned short* t       = xb;  // safe alias: xb dead after QKV GEMM

  cvt_all<<<15384, 256, 0, stream>>>(x, Wq, Wk, Wv, Wo, bq, bk, bv, xb, wcat, wo_b, biascat);

  // QKV: (8192x1024) x (6144x1024)^T -> 8192x6144 bf16  (8-phase pipeline)
  gemm256<<<dim3(24, 32), 512, 0, stream>>>(xb, wcat, biascat, qkv, 8192, 6144, 1024);
  // attention + permute/sum scatter -> t (8192x1024 bf16)
  attn_scatter<<<2048, 256, 0, stream>>>(qkv, t);
  // final: t x Wo^T + bo -> fp32 out
  gemm_bt<float><<<dim3(8, 64), 256, 0, stream>>>(t, wo_b, bo, out, 8192, 1024, 1024);
}

// Round 9
// 278.577 us; speedup vs baseline: 1.0643x; 1.0429x over previous
//
#include <hip/hip_runtime.h>

// ---------------------------------------------------------------------------
// MultiQueryAttention: B=4 S=2048 E=1024 H=16 D=64 Q=4
// ref: q=x@Wq^T+bq (per qi), k=x@Wk^T+bk, v=x@Wv^T+bv
//      scores[qi,b,s,h,g] = dot_d(q[h],k[g])/8 ; softmax over g (16 heads!)
//      out[qi,b,s,h,d] = sum_g p*v[g,d]
//      t[b, 128h + s/16, 64(s%16)+d] = sum_qi out   (torch transpose+reshape)
//      final = t @ Wo^T + bo   (fp32 out)
// ---------------------------------------------------------------------------

typedef __bf16 bf16x8 __attribute__((ext_vector_type(8)));
typedef float f32x4 __attribute__((ext_vector_type(4)));
typedef float f32x16 __attribute__((ext_vector_type(16)));

__device__ __forceinline__ unsigned short f2b(float f) {
  unsigned u = __float_as_uint(f);
  return (unsigned short)((u + 0x7fffu + ((u >> 16) & 1u)) >> 16);  // RNE
}

__device__ __forceinline__ void async16(const void* g, void* l) {
  __builtin_amdgcn_global_load_lds(
      (const __attribute__((address_space(1))) void*)g,
      (__attribute__((address_space(3))) void*)l, 16, 0, 0);
}

// ------------------- fused fp32->bf16 convert + bias concat ------------------
__global__ __launch_bounds__(256) void cvt_all(
    const float* __restrict__ x, const float* __restrict__ Wq, const float* __restrict__ Wk,
    const float* __restrict__ Wv, const float* __restrict__ Wo, const float* __restrict__ bq,
    const float* __restrict__ bk, const float* __restrict__ bv,
    unsigned short* __restrict__ xb, unsigned short* __restrict__ wcat,
    unsigned short* __restrict__ wo_b, float* __restrict__ biascat) {
  if (blockIdx.x >= 15360) {
    int j = (blockIdx.x - 15360) * 256 + threadIdx.x;  // 0..6143
    if (j < 6144) {
      float v = (j < 4096) ? bq[j] : (j < 5120 ? bk[j - 4096] : bv[j - 5120]);
      biascat[j] = v;
    }
    return;
  }
  int i = blockIdx.x * 256 + threadIdx.x;
  const float* s;
  unsigned short* d;
  int off;
  if (i < 2097152)      { s = x;  d = xb;             off = i; }
  else if (i < 3145728) { s = Wq; d = wcat;           off = i - 2097152; }
  else if (i < 3407872) { s = Wk; d = wcat + 4194304; off = i - 3145728; }
  else if (i < 3670016) { s = Wv; d = wcat + 5242880; off = i - 3407872; }
  else                  { s = Wo; d = wo_b;           off = i - 3670016; }
  float4 v = ((const float4*)s)[off];
  uint2 o;
  o.x = (unsigned)f2b(v.x) | ((unsigned)f2b(v.y) << 16);
  o.y = (unsigned)f2b(v.z) | ((unsigned)f2b(v.w) << 16);
  ((uint2*)d)[off] = o;
}

// ------------------ 256x256 deep-pipelined GEMM (QKV) -----------------------
// R3 EXACT (verified best across R2-R8: 114.3us, MfmaUtil 39%, 0 conflicts).
// C = A * Bt^T + bias, bf16 out. 8 waves 2(M)x4(N); per-wave 128x64 = 4x2
// frags of 32x32. LDS: 4-deep ring of BK=32 K-tiles = 128 KiB, 1 block/CU.
//
// PAIR-ROW SWIZZLE (0 conflicts measured): granule g (16B) of row r at phys
// p = (2g+(r&1)) ^ ((r>>1)&7) within pair (r>>1). Store: linear LDS dest
// (global_load_lds), pre-swizzled GLOBAL source. Read:
// p = (4ks + 2*lhi + (l31&1)) ^ ((l31>>1)&7).
//
// ONE barrier per K-tile; stage kt+2 mid-iteration; counted vmcnt(4).
// Ledger: R4 dist-2 prefetch 151us; R5 setprio 129.7us (1 block/CU -> no
// co-block to arbitrate); R6 consumption-order 144us; R2/R8 8-phase 139.7/
// 132us. All reverted.
__global__ __launch_bounds__(512, 2) void gemm256(
    const unsigned short* __restrict__ A, const unsigned short* __restrict__ Bt,
    const float* __restrict__ bias, unsigned short* __restrict__ C,
    int M, int N, int K) {
  __shared__ __align__(16) unsigned short As[4][8192];
  __shared__ __align__(16) unsigned short Bs[4][8192];
  const int t = threadIdx.x;
  const int lane = t & 63, w = t >> 6;
  const int l31 = lane & 31, lhi = lane >> 5;
  const int wm = (w >> 2) * 128, wn = (w & 3) * 64;
  const int bm0 = blockIdx.y * 256, bn0 = blockIdx.x * 256;

  const int p0 = t & 7, pr0 = t >> 3;
  const int u0 = p0 ^ (pr0 & 7);
  const size_t aoff0 = (size_t)(2 * pr0 + (u0 & 1)) * K + (u0 >> 1) * 8;
  const unsigned short* aS0 = A + (size_t)bm0 * K + aoff0;
  const unsigned short* aS1 = aS0 + (size_t)128 * K;
  const unsigned short* bS0 = Bt + (size_t)bn0 * K + aoff0;
  const unsigned short* bS1 = bS0 + (size_t)128 * K;
  const int d0 = t * 8, d1 = d0 + 4096;

  const int plo = 2 * lhi + (l31 & 1);
  const int pswz = (l31 >> 1) & 7;
  const int pg0 = ((0 + plo) ^ pswz) * 8;
  const int pg1 = ((4 + plo) ^ pswz) * 8;
  int prA[4], prB[2];
#pragma unroll
  for (int mi = 0; mi < 4; ++mi) prA[mi] = ((wm + mi * 32 + l31) >> 1) * 64;
#pragma unroll
  for (int nj = 0; nj < 2; ++nj) prB[nj] = ((wn + nj * 32 + l31) >> 1) * 64;

  f32x16 acc[4][2];
#pragma unroll
  for (int mi = 0; mi < 4; ++mi)
#pragma unroll
    for (int nj = 0; nj < 2; ++nj)
#pragma unroll
      for (int e = 0; e < 16; ++e) acc[mi][nj][e] = 0.f;

#define STG_A(kt_) do { const int b_ = (kt_) & 3; const int ko_ = (kt_) * 32; \
    async16(aS0 + ko_, &As[b_][d0]); async16(aS1 + ko_, &As[b_][d1]); } while (0)
#define STG_B(kt_) do { const int b_ = (kt_) & 3; const int ko_ = (kt_) * 32; \
    async16(bS0 + ko_, &Bs[b_][d0]); async16(bS1 + ko_, &Bs[b_][d1]); } while (0)

  const int NT = K >> 5;
  STG_A(0); STG_B(0); STG_A(1); STG_B(1);
  asm volatile("s_waitcnt vmcnt(4)" ::: "memory");
  asm volatile("s_barrier" ::: "memory");

  for (int kt = 0; kt < NT; ++kt) {
    const int bi = kt & 3;
    const unsigned short* as_ = As[bi];
    const unsigned short* bs_ = Bs[bi];

    bf16x8 af[4][2], bfv[2][2];
#pragma unroll
    for (int mi = 0; mi < 4; ++mi) {
      af[mi][0] = *(const bf16x8*)(as_ + prA[mi] + pg0);
      af[mi][1] = *(const bf16x8*)(as_ + prA[mi] + pg1);
    }
#pragma unroll
    for (int nj = 0; nj < 2; ++nj) {
      bfv[nj][0] = *(const bf16x8*)(bs_ + prB[nj] + pg0);
      bfv[nj][1] = *(const bf16x8*)(bs_ + prB[nj] + pg1);
    }
    if (kt + 2 < NT) { STG_A(kt + 2); STG_B(kt + 2); }

#pragma unroll
    for (int mi = 0; mi < 4; ++mi)
#pragma unroll
      for (int nj = 0; nj < 2; ++nj) {
        acc[mi][nj] = __builtin_amdgcn_mfma_f32_32x32x16_bf16(af[mi][0], bfv[nj][0], acc[mi][nj], 0, 0, 0);
        acc[mi][nj] = __builtin_amdgcn_mfma_f32_32x32x16_bf16(af[mi][1], bfv[nj][1], acc[mi][nj], 0, 0, 0);
      }

    if (kt + 2 < NT) {
      asm volatile("s_waitcnt vmcnt(4)" ::: "memory");
    } else if (kt + 1 < NT) {
      asm volatile("s_waitcnt vmcnt(0)" ::: "memory");
    }
    asm volatile("s_barrier" ::: "memory");
  }
#undef STG_A
#undef STG_B

#pragma unroll
  for (int mi = 0; mi < 4; ++mi) {
#pragma unroll
    for (int nj = 0; nj < 2; ++nj) {
      int gc = bn0 + wn + nj * 32 + l31;
      float bsv = bias[gc];
#pragma unroll
      for (int reg = 0; reg < 16; ++reg) {
        int gr = bm0 + wm + mi * 32 + (reg & 3) + 8 * (reg >> 2) + 4 * lhi;
        C[(size_t)gr * N + gc] = f2b(acc[mi][nj][reg] + bsv);
      }
    }
  }
}

// ------------- 128x128 R3-structure GEMM (final projection) -----------------
// Same verified loop skeleton as gemm256 (ring-4 BK=32, pair-row swizzle,
// 1 barrier/K-tile, counted vmcnt(4)) at 128x128 / 4 waves / 64 KiB LDS ->
// 2 blocks/CU (cross-block LDS/MFMA overlap). fp32 out.
__global__ __launch_bounds__(256, 2) void gemm128(
    const unsigned short* __restrict__ A, const unsigned short* __restrict__ Bt,
    const float* __restrict__ bias, float* __restrict__ C,
    int M, int N, int K) {
  __shared__ __align__(16) unsigned short As[4][4096];
  __shared__ __align__(16) unsigned short Bs[4][4096];
  const int t = threadIdx.x;
  const int lane = t & 63, w = t >> 6;
  const int l31 = lane & 31, lhi = lane >> 5;
  const int wm = (w >> 1) * 64, wn = (w & 1) * 64;
  const int bm0 = blockIdx.y * 128, bn0 = blockIdx.x * 128;

  // staging: thread t -> slots t (rows 0..63) and t+256 (rows 64..127)
  const int p0 = t & 7, pr0 = t >> 3;               // pr0 0..31
  const int u0 = p0 ^ (pr0 & 7);
  const size_t aoff0 = (size_t)(2 * pr0 + (u0 & 1)) * K + (u0 >> 1) * 8;
  const unsigned short* aS0 = A + (size_t)bm0 * K + aoff0;
  const unsigned short* aS1 = aS0 + (size_t)64 * K;  // +64 rows (pair+32, same u)
  const unsigned short* bS0 = Bt + (size_t)bn0 * K + aoff0;
  const unsigned short* bS1 = bS0 + (size_t)64 * K;
  const int d0 = t * 8, d1 = d0 + 2048;

  const int plo = 2 * lhi + (l31 & 1);
  const int pswz = (l31 >> 1) & 7;
  const int pg0 = ((0 + plo) ^ pswz) * 8;
  const int pg1 = ((4 + plo) ^ pswz) * 8;
  int prA[2], prB[2];
#pragma unroll
  for (int mi = 0; mi < 2; ++mi) prA[mi] = ((wm + mi * 32 + l31) >> 1) * 64;
#pragma unroll
  for (int nj = 0; nj < 2; ++nj) prB[nj] = ((wn + nj * 32 + l31) >> 1) * 64;

  f32x16 acc[2][2];
#pragma unroll
  for (int mi = 0; mi < 2; ++mi)
#pragma unroll
    for (int nj = 0; nj < 2; ++nj)
#pragma unroll
      for (int e = 0; e < 16; ++e) acc[mi][nj][e] = 0.f;

#define STG_A(kt_) do { const int b_ = (kt_) & 3; const int ko_ = (kt_) * 32; \
    async16(aS0 + ko_, &As[b_][d0]); async16(aS1 + ko_, &As[b_][d1]); } while (0)
#define STG_B(kt_) do { const int b_ = (kt_) & 3; const int ko_ = (kt_) * 32; \
    async16(bS0 + ko_, &Bs[b_][d0]); async16(bS1 + ko_, &Bs[b_][d1]); } while (0)

  const int NT = K >> 5;
  STG_A(0); STG_B(0); STG_A(1); STG_B(1);
  asm volatile("s_waitcnt vmcnt(4)" ::: "memory");
  asm volatile("s_barrier" ::: "memory");

  for (int kt = 0; kt < NT; ++kt) {
    const int bi = kt & 3;
    const unsigned short* as_ = As[bi];
    const unsigned short* bs_ = Bs[bi];

    bf16x8 af[2][2], bfv[2][2];
#pragma unroll
    for (int mi = 0; mi < 2; ++mi) {
      af[mi][0] = *(const bf16x8*)(as_ + prA[mi] + pg0);
      af[mi][1] = *(const bf16x8*)(as_ + prA[mi] + pg1);
    }
#pragma unroll
    for (int nj = 0; nj < 2; ++nj) {
      bfv[nj][0] = *(const bf16x8*)(bs_ + prB[nj] + pg0);
      bfv[nj][1] = *(const bf16x8*)(bs_ + prB[nj] + pg1);
    }
    if (kt + 2 < NT) { STG_A(kt + 2); STG_B(kt + 2); }

#pragma unroll
    for (int mi = 0; mi < 2; ++mi)
#pragma unroll
      for (int nj = 0; nj < 2; ++nj) {
        acc[mi][nj] = __builtin_amdgcn_mfma_f32_32x32x16_bf16(af[mi][0], bfv[nj][0], acc[mi][nj], 0, 0, 0);
        acc[mi][nj] = __builtin_amdgcn_mfma_f32_32x32x16_bf16(af[mi][1], bfv[nj][1], acc[mi][nj], 0, 0, 0);
      }

    if (kt + 2 < NT) {
      asm volatile("s_waitcnt vmcnt(4)" ::: "memory");
    } else if (kt + 1 < NT) {
      asm volatile("s_waitcnt vmcnt(0)" ::: "memory");
    }
    asm volatile("s_barrier" ::: "memory");
  }
#undef STG_A
#undef STG_B

#pragma unroll
  for (int mi = 0; mi < 2; ++mi) {
#pragma unroll
    for (int nj = 0; nj < 2; ++nj) {
      int gc = bn0 + wn + nj * 32 + l31;
      float bsv = bias[gc];
#pragma unroll
      for (int reg = 0; reg < 16; ++reg) {
        int gr = bm0 + wm + mi * 32 + (reg & 3) + 8 * (reg >> 2) + 4 * lhi;
        C[(size_t)gr * N + gc] = acc[mi][nj][reg] + bsv;
      }
    }
  }
}

// ------------------- per-position head-softmax attention --------------------
// R9: P stride 17->20 (float4-aligned; store 2-way, load <=2-way bank aliasing
// = free per m136), pf gather 8 scalar reads -> 2 b128 reads; e/sum -> e*rcp.
__global__ __launch_bounds__(256) void attn_scatter(const unsigned short* __restrict__ qkv,
                                                    unsigned short* __restrict__ t) {
  __shared__ __align__(16) unsigned short vs[4][1024];
  __shared__ __align__(16) float ps[4][16 * 20];
  const int w = threadIdx.x >> 6, lane = threadIdx.x & 63;
  const int pos = blockIdx.x * 4 + w;  // 0..8191
  const int b = pos >> 11, s = pos & 2047;
  const unsigned short* row = qkv + (size_t)pos * 6144;
  unsigned short* vw = vs[w];
  float* pw = ps[w];
  const int lr = lane & 15, lq = lane >> 4;

  {
    const uint4* sv = (const uint4*)(row + 5120);
    uint4* dv = (uint4*)vw;
    dv[lane * 2] = sv[lane * 2];
    dv[lane * 2 + 1] = sv[lane * 2 + 1];
  }
  bf16x8 kf0 = *(const bf16x8*)(row + 4096 + lr * 64 + lq * 8);
  bf16x8 kf1 = *(const bf16x8*)(row + 4096 + lr * 64 + 32 + lq * 8);

  bf16x8 vf[4];
#pragma unroll
  for (int dc = 0; dc < 4; ++dc) {
#pragma unroll
    for (int j = 0; j < 8; ++j) vf[dc][j] = (__bf16)0.0f;
    if (lq < 2) {
      const __bf16* vb = (const __bf16*)vw;
#pragma unroll
      for (int j = 0; j < 8; ++j)
        vf[dc][j] = vb[(lq * 8 + j) * 64 + dc * 16 + lr];
    }
  }

  f32x4 acc[4];
#pragma unroll
  for (int dc = 0; dc < 4; ++dc) acc[dc] = (f32x4){0.f, 0.f, 0.f, 0.f};

#pragma unroll
  for (int qi = 0; qi < 4; ++qi) {
    bf16x8 qf0 = *(const bf16x8*)(row + qi * 1024 + lr * 64 + lq * 8);
    bf16x8 qf1 = *(const bf16x8*)(row + qi * 1024 + lr * 64 + 32 + lq * 8);
    f32x4 sc = {0.f, 0.f, 0.f, 0.f};
    sc = __builtin_amdgcn_mfma_f32_16x16x32_bf16(qf0, kf0, sc, 0, 0, 0);
    sc = __builtin_amdgcn_mfma_f32_16x16x32_bf16(qf1, kf1, sc, 0, 0, 0);
#pragma unroll
    for (int r = 0; r < 4; ++r) {
      float e = __expf(sc[r] * 0.125f);  // scores bounded, max-sub unnecessary
      float sum = e;
#pragma unroll
      for (int d = 1; d < 16; d <<= 1) sum += __shfl_xor(sum, d);
      pw[(lq * 4 + r) * 20 + lr] = e * __builtin_amdgcn_rcpf(sum);
    }
    // P B-frag: B[k=lq*8+j][n=lr] = P[lr][lq*8+j]; consecutive j -> 2x b128
    bf16x8 pf;
#pragma unroll
    for (int j = 0; j < 8; ++j) pf[j] = (__bf16)0.0f;
    if (lq < 2) {
      const float4* pp = (const float4*)(pw + lr * 20 + lq * 8);
      float4 pa = pp[0], pb = pp[1];
      pf[0] = (__bf16)pa.x; pf[1] = (__bf16)pa.y;
      pf[2] = (__bf16)pa.z; pf[3] = (__bf16)pa.w;
      pf[4] = (__bf16)pb.x; pf[5] = (__bf16)pb.y;
      pf[6] = (__bf16)pb.z; pf[7] = (__bf16)pb.w;
    }
#pragma unroll
    for (int dc = 0; dc < 4; ++dc)
      acc[dc] = __builtin_amdgcn_mfma_f32_16x16x32_bf16(vf[dc], pf, acc[dc], 0, 0, 0);
  }

  size_t base = ((size_t)(b * 2048 + 128 * lr + (s >> 4))) * 1024 + 64 * (s & 15) + lq * 4;
#pragma unroll
  for (int dc = 0; dc < 4; ++dc) {
    uint2 u;
    u.x = (unsigned)f2b(acc[dc][0]) | ((unsigned)f2b(acc[dc][1]) << 16);
    u.y = (unsigned)f2b(acc[dc][2]) | ((unsigned)f2b(acc[dc][3]) << 16);
    *(uint2*)(t + base + dc * 16) = u;
  }
}

// ---------------------------------------------------------------------------
extern "C" void kernel_launch(void* const* d_in, const int* in_sizes, int n_in,
                              void* d_out, int out_size, void* d_ws, size_t ws_size,
                              hipStream_t stream) {
  const float* x  = (const float*)d_in[0];
  const float* Wq = (const float*)d_in[1];
  const float* bq = (const float*)d_in[2];
  const float* Wk = (const float*)d_in[3];
  const float* bk = (const float*)d_in[4];
  const float* Wv = (const float*)d_in[5];
  const float* bv = (const float*)d_in[6];
  const float* Wo = (const float*)d_in[7];
  const float* bo = (const float*)d_in[8];
  float* out = (float*)d_out;

  char* ws = (char*)d_ws;
  unsigned short* xb      = (unsigned short*)(ws + 0);         // 8192x1024 bf16 (16MB); aliased as t later
  unsigned short* wcat    = (unsigned short*)(ws + 16777216);  // 6144x1024 bf16 (12MB): Wq|Wk|Wv
  unsigned short* wo_b    = (unsigned short*)(ws + 29360128);  // 1024x1024 bf16 (2MB)
  float*          biascat = (float*)(ws + 31457280);           // 6144 fp32
  unsigned short* qkv     = (unsigned short*)(ws + 31481856);  // 8192x6144 bf16 (96MB)
  unsigned short* t       = xb;  // safe alias: xb dead after QKV GEMM

  cvt_all<<<15384, 256, 0, stream>>>(x, Wq, Wk, Wv, Wo, bq, bk, bv, xb, wcat, wo_b, biascat);

  // QKV: (8192x1024) x (6144x1024)^T -> 8192x6144 bf16  (R3 structure)
  gemm256<<<dim3(24, 32), 512, 0, stream>>>(xb, wcat, biascat, qkv, 8192, 6144, 1024);
  // attention + permute/sum scatter -> t (8192x1024 bf16)
  attn_scatter<<<2048, 256, 0, stream>>>(qkv, t);
  // final: t x Wo^T + bo -> fp32 out  (R3 structure @128^2, 2 blocks/CU)
  gemm128<<<dim3(8, 64), 256, 0, stream>>>(t, wo_b, bo, out, 8192, 1024, 1024);
}